// Round 6
// baseline (487.121 us; speedup 1.0000x reference)
//
#include <hip/hip_runtime.h>

#define HID 32
#define SEQ 512
#define WAVES_PER_BLOCK 4
#define BLOCK (WAVES_PER_BLOCK * 64)

#define LOG2E  1.4426950408889634f
#define LOG2E2 2.8853900817779268f

typedef float v2f __attribute__((ext_vector_type(2)));

// broadcast lane `lane`'s value of v via v_readlane -> SGPR
__device__ __forceinline__ float bcastlane(float v, int lane) {
    return __int_as_float(__builtin_amdgcn_readlane(__float_as_int(v), lane));
}

// act(x) = 1 - m * rcp(1 + exp2(s*x)); sigmoid: m=1,s=log2e  tanh: m=2,s=2log2e
// saturates cleanly at +/-inf (rcp(inf)=0), never NaN for finite x
__device__ __forceinline__ float act_f(float x, float m, float s) {
    const float e = __builtin_amdgcn_exp2f(s * x);
    return __builtin_fmaf(-m, __builtin_amdgcn_rcpf(1.0f + e), 1.0f);
}

// packed 2xfp32 FMA: acc.lo += h.lo*w.lo ; acc.hi += h.hi*w.hi
// h in SGPR pair (readlane results are uniform), w/acc in VGPR pairs.
__device__ __forceinline__ void pk_fma(v2f& acc, const v2f& w, const v2f& h) {
    asm("v_pk_fma_f32 %0, %2, %1, %0" : "+v"(acc) : "v"(w), "s"(h));
}

__global__
__attribute__((amdgpu_flat_work_group_size(BLOCK, BLOCK)))
__attribute__((amdgpu_waves_per_eu(2, 2)))   // 2 waves/EU -> 256-VGPR budget
                                             // (R5: first config where weights
                                             //  actually stayed register-resident)
void lstm_fused_kernel(
    const float* __restrict__ x,       // [B, T, 1]
    const float* __restrict__ W_ih,    // [4H, 1]
    const float* __restrict__ W_hh,    // [4H, H] row-major
    const float* __restrict__ b_ih,    // [4H]
    const float* __restrict__ b_hh,    // [4H]
    const float* __restrict__ W_head,  // [1, H]
    const float* __restrict__ b_head,  // [1]
    float* __restrict__ out)           // [B, 1]
{
    const int tid  = threadIdx.x;
    const int lane = tid & 63;
    const int k    = lane & 31;   // hidden unit owned by this lane
    const int p    = lane >> 5;   // 0: rows (i, g)   1: rows (f, o)
    const int wave = tid >> 6;
    const int b    = blockIdx.x * WAVES_PER_BLOCK + wave;  // one batch per wave

    // gate-row ownership: rowA = lane (i p=0 / f p=1), rowB = 64+lane (g / o)
    const int rowA = lane;
    const int rowB = 64 + lane;

    // W_hh rows into VGPR pairs (j-packed): wX2[q] = (w[2q], w[2q+1])
    v2f wA2[HID / 2], wB2[HID / 2];
    {
        const float4* WA4 = (const float4*)(W_hh + rowA * HID);
        const float4* WB4 = (const float4*)(W_hh + rowB * HID);
#pragma unroll
        for (int q = 0; q < HID / 4; ++q) {
            const float4 a = WA4[q], bb = WB4[q];
            wA2[2*q]   = (v2f){a.x, a.y};
            wA2[2*q+1] = (v2f){a.z, a.w};
            wB2[2*q]   = (v2f){bb.x, bb.y};
            wB2[2*q+1] = (v2f){bb.z, bb.w};
        }
    }
#pragma unroll
    for (int q = 0; q < HID / 2; ++q) {
        asm volatile("" : "+v"(wA2[q]));  // opaque pin: no remat/sink into loop
        asm volatile("" : "+v"(wB2[q]));
    }

    const float biasA = b_ih[rowA] + b_hh[rowA];
    const float biasB = b_ih[rowB] + b_hh[rowB];
    const float uA = W_ih[rowA];
    const float uB = W_ih[rowB];

    // gate A is ALWAYS sigmoid. gate B: tanh on p=0 (g), sigmoid on p=1 (o).
    const float mB = p ? 1.0f  : 2.0f;
    const float sB = p ? LOG2E : LOG2E2;

    // wave-uniform batch index -> x reads go through the scalar (SMEM) pipe
    const int b_s = __builtin_amdgcn_readfirstlane(b);
    const float* xb = x + (size_t)b_s * SEQ;  // I == 1

    // real c,h live on p=1 lanes (lane 32+k holds unit k); p=0 copies are
    // garbage-but-bounded (inf saturates through rcp -> never NaN)
    float h = 0.0f, c = 0.0f;

    for (int t = 0; t < SEQ; ++t) {
        const float xt = xb[t];
        // 4 independent packed accumulator chains (2 per gate) for ILP
        v2f accA0 = {__builtin_fmaf(xt, uA, biasA), 0.0f};
        v2f accB0 = {__builtin_fmaf(xt, uB, biasB), 0.0f};
        v2f accA1 = {0.0f, 0.0f};
        v2f accB1 = {0.0f, 0.0f};
#pragma unroll
        for (int q = 0; q < HID / 4; ++q) {
            v2f h0, h1;  // h_j lives on lane 32+j; readlane -> SGPR pairs
            h0.x = bcastlane(h, 32 + 4*q + 0);
            h0.y = bcastlane(h, 32 + 4*q + 1);
            h1.x = bcastlane(h, 32 + 4*q + 2);
            h1.y = bcastlane(h, 32 + 4*q + 3);
            pk_fma(accA0, wA2[2*q],     h0);
            pk_fma(accB0, wB2[2*q],     h0);
            pk_fma(accA1, wA2[2*q + 1], h1);
            pk_fma(accB1, wB2[2*q + 1], h1);
        }
        const float pA = (accA0.x + accA0.y) + (accA1.x + accA1.y);
        const float pB = (accB0.x + accB0.y) + (accB1.x + accB1.y);

        const float actA = act_f(pA, 1.0f, LOG2E);  // sigmoid: i (p=0) / f (p=1)
        const float actB = act_f(pB, mB, sB);       // tanh g (p=0) / sigmoid o (p=1)

        // p=0 computes i*g locally; ship to p=1 (reverse direction unused)
        const float sw = __shfl_xor(actA * actB, 32);

        // on p=1 lanes: c = f*c + i*g ; h = o * tanh(c)
        c = __builtin_fmaf(actA, c, sw);
        const float tc = act_f(c, 2.0f, LOG2E2);
        h = actB * tc;
    }

    // head: h_k on lane 32+k -> mask p=0 half, reduce, lane 0 writes
    float v = p ? h * W_head[k] : 0.0f;
#pragma unroll
    for (int off = 32; off >= 1; off >>= 1)
        v += __shfl_xor(v, off);
    if (lane == 0) out[b] = v + b_head[0];
}

extern "C" void kernel_launch(void* const* d_in, const int* in_sizes, int n_in,
                              void* d_out, int out_size, void* d_ws, size_t ws_size,
                              hipStream_t stream) {
    const float* x      = (const float*)d_in[0];
    const float* W_ih   = (const float*)d_in[1];
    const float* W_hh   = (const float*)d_in[2];
    const float* b_ih   = (const float*)d_in[3];
    const float* b_hh   = (const float*)d_in[4];
    const float* W_head = (const float*)d_in[5];
    const float* b_head = (const float*)d_in[6];
    float* out = (float*)d_out;

    const int B = in_sizes[0] / SEQ;            // 4096
    const int grid = B / WAVES_PER_BLOCK;       // 1024 blocks, 1 batch per wave

    lstm_fused_kernel<<<grid, BLOCK, 0, stream>>>(
        x, W_ih, W_hh, b_ih, b_hh, W_head, b_head, out);
}